// Round 3
// baseline (365.752 us; speedup 1.0000x reference)
//
#include <hip/hip_runtime.h>
#include <stdint.h>

#define BATCH 16384
#define IN_F 2048
#define OUT_F 2048

typedef unsigned short u16;
typedef __attribute__((ext_vector_type(8))) short bf16x8;
typedef __attribute__((ext_vector_type(16))) float f32x16;

__device__ __forceinline__ u16 f2bf(float f) {
  union { float f; uint32_t u; } v; v.f = f;
  uint32_t u = v.u;
  u += 0x7FFFu + ((u >> 16) & 1u);   // round-to-nearest-even
  return (u16)(u >> 16);
}

// ---- prologue: fused fp32 -> bf16 conversion (x and w*mask in one launch) ----

__global__ void cvt_fused(const float4* __restrict__ x, const float4* __restrict__ w,
                          const float4* __restrict__ m, u16* __restrict__ xb,
                          u16* __restrict__ wb) {
  const int NX = BATCH * IN_F / 4;
  int i = blockIdx.x * 256 + threadIdx.x;
  if (i < NX) {
    float4 v = x[i];
    uint2 p;
    p.x = (uint32_t)f2bf(v.x) | ((uint32_t)f2bf(v.y) << 16);
    p.y = (uint32_t)f2bf(v.z) | ((uint32_t)f2bf(v.w) << 16);
    ((uint2*)xb)[i] = p;
  } else {
    int j = i - NX;
    float4 wv = w[j];
    float4 mv = m[j];
    uint2 p;
    p.x = (uint32_t)f2bf(wv.x * mv.x) | ((uint32_t)f2bf(wv.y * mv.y) << 16);
    p.y = (uint32_t)f2bf(wv.z * mv.z) | ((uint32_t)f2bf(wv.w * mv.w) << 16);
    ((uint2*)wb)[j] = p;
  }
}

// ---- async global->LDS 16B copy ----

__device__ __forceinline__ void async_cp16(const void* g, void* l) {
  __builtin_amdgcn_global_load_lds(
      (const __attribute__((address_space(1))) void*)g,
      (__attribute__((address_space(3))) void*)l,
      16, 0, 0);
}

// ---- bf16 MFMA GEMM: C[M][N] = A[M][K] * B[N][K]^T + bias ----
// 256x256 tile, BK=32, 512 threads = 8 waves (2M x 4N), wave tile 128x64.
// THIS ROUND: 32x32x16 MFMA (m119: 2495 TF pipe vs ~2100 for 16x16 -> ~17%
// fewer matrix-pipe cycles for the same FLOPs; half the MFMA instructions),
// plus K-loop unrolled x4 so the ring slot is a literal (LDS addrs fold to
// base+imm, cutting VALU pointer math).
// Pipeline unchanged (verified r2): 4-slot LDS ring (128 KiB), depth-3
// prefetch, counted vmcnt(4) once per iter, one barrier per iter; fragments
// for tile t+1 ds_read during iter t's MFMA clusters.
// Invariant at end of iter t (after vmcnt(4)): tiles <= t+2 resident,
// tile t+3 in flight (4 loads/thread). Prefetch reads of slot (t+1)&3 during
// iter t are safe; stage target slot (t+3)&3 = (t-1)&3 was last read in
// iter t-1 (lgkm-drained before its MFMA use, barrier since).
// Swizzle (verified 0 conflicts): physical 16B chunk c of row r holds
// logical chunk c ^ ((r>>1)&3); staging pre-swizzles the global source
// column, reads apply the same XOR. For 32x32 frags (rows lane&31, k-group
// lane>>5) this yields 8 lanes per bank-quad = structural minimum for b128.
// Operand layouts (32x32x16_bf16): A/B lane l holds row/col l&31,
// k = (l>>5)*8+e. C/D [m74/m101]: col=lane&31, row=(reg&3)+8*(reg>>2)+4*(lane>>5).

#define BK 32
#define NT (IN_F / BK)   // 64 K-tiles

__global__ __launch_bounds__(512, 2) void gemm_bf16(const u16* __restrict__ A,
                                                    const u16* __restrict__ B,
                                                    const float* __restrict__ bias,
                                                    float* __restrict__ C) {
  __shared__ __align__(128) char smem[4 * 32768];
  const int K = IN_F, N = OUT_F;
  const int tid = threadIdx.x;
  const int lane = tid & 63, wave = tid >> 6;
  const int wm = wave >> 2;          // 0..1  (M half)
  const int wn = wave & 3;           // 0..3  (N quarter)
  const long bn = (long)blockIdx.x * 256;   // x = bn-stripe: each XCD keeps its B panel L2-resident
  const long bm = (long)blockIdx.y * 256;

  // ---- staging: thread tid stages row sr=tid>>2, phys chunk sc=tid&3
  const int sr = tid >> 2, sc = tid & 3;
  const int scs = sc ^ ((sr >> 1) & 3);
  const u16* gA = A + (bm + sr) * K + scs * 8;
  const u16* gB = B + (bn + sr) * K + scs * 8;
  const long hiK = 128L * K;                 // (r+128)>>1 == r>>1 (mod 4): same swizzle
  const int ldst = tid * 16;

  auto stageA = [&](int slot, int kt) {
    char* sb = smem + slot * 32768;
    const long ko = (long)kt * BK;
    async_cp16(gA + ko, sb + ldst);
    async_cp16(gA + hiK + ko, sb + 8192 + ldst);
  };
  auto stageB = [&](int slot, int kt) {
    char* sb = smem + slot * 32768 + 16384;
    const long ko = (long)kt * BK;
    async_cp16(gB + ko, sb + ldst);
    async_cp16(gB + hiK + ko, sb + 8192 + ldst);
  };

  // ---- fragment read geometry (32x32 frags)
  const int r32 = lane & 31;              // row within 32-row subtile
  const int kq = lane >> 5;               // k-group (8 elems each)
  const int xr = (r32 >> 1) & 3;          // swizzle term
  const int co0 = ((0 + kq) ^ xr) * 16;   // ks=0: logical chunk kq
  const int co1 = ((2 + kq) ^ xr) * 16;   // ks=1: logical chunk 2+kq
  const int abase = wm * 8192 + r32 * 64;
  const int bbase = 16384 + wn * 4096 + r32 * 64;

#define LDA(SLOT, SUB, KS) \
  (*(const bf16x8*)(smem + (SLOT) * 32768 + abase + (SUB) * 2048 + ((KS) ? co1 : co0)))
#define LDB(SLOT, J, KS) \
  (*(const bf16x8*)(smem + (SLOT) * 32768 + bbase + (J) * 2048 + ((KS) ? co1 : co0)))

  f32x16 acc[4][2];
#pragma unroll
  for (int i = 0; i < 4; i++)
#pragma unroll
    for (int j = 0; j < 2; j++)
#pragma unroll
      for (int r = 0; r < 16; r++) acc[i][j][r] = 0.0f;

  // ---- prologue: stage tiles 0,1,2; retire tiles 0 and 1 (vmcnt 4)
  stageA(0, 0); stageB(0, 0);
  stageA(1, 1); stageB(1, 1);
  stageA(2, 2); stageB(2, 2);
  asm volatile("s_waitcnt vmcnt(4)" ::: "memory");
  __builtin_amdgcn_s_barrier();

  // preload tile-0 fragments (A M-half0 subtiles 0,1; B both N-frags) into set A
  bf16x8 afA[4], bfA[4], afB[4], bfB[4];
#pragma unroll
  for (int i = 0; i < 2; i++) {
    afA[i * 2 + 0] = LDA(0, i, 0);
    afA[i * 2 + 1] = LDA(0, i, 1);
    bfA[i * 2 + 0] = LDB(0, i, 0);
    bfA[i * 2 + 1] = LDB(0, i, 1);
  }

  // BODY: stage t+3; read A M-half1 under cluster 1; read next-iter mh0/B
  // (tile t+1) under cluster 2; counted vmcnt; one barrier. SLOT is a literal.
#define BODY(T, SLOT, curA, curB, nxtA, nxtB)                                    \
  do {                                                                           \
    const int t_ = (T);                                                          \
    const int kt3_ = (t_ + 3 < NT) ? (t_ + 3) : (NT - 1);                        \
    stageA(((SLOT) + 3) & 3, kt3_);                                              \
    stageB(((SLOT) + 3) & 3, kt3_);                                              \
    bf16x8 af1_[4];                                                              \
    _Pragma("unroll")                                                            \
    for (int i = 0; i < 2; i++) {                                                \
      af1_[i * 2 + 0] = LDA(SLOT, 2 + i, 0);                                     \
      af1_[i * 2 + 1] = LDA(SLOT, 2 + i, 1);                                     \
    }                                                                            \
    __builtin_amdgcn_s_setprio(1);                                               \
    _Pragma("unroll")                                                            \
    for (int ks = 0; ks < 2; ks++)                                               \
      _Pragma("unroll")                                                          \
      for (int i = 0; i < 2; i++)                                                \
        _Pragma("unroll")                                                        \
        for (int j = 0; j < 2; j++)                                              \
          acc[i][j] = __builtin_amdgcn_mfma_f32_32x32x16_bf16(                   \
              curA[i * 2 + ks], curB[j * 2 + ks], acc[i][j], 0, 0, 0);           \
    __builtin_amdgcn_s_setprio(0);                                               \
    _Pragma("unroll")                                                            \
    for (int i = 0; i < 2; i++) {                                                \
      nxtA[i * 2 + 0] = LDA(((SLOT) + 1) & 3, i, 0);                             \
      nxtA[i * 2 + 1] = LDA(((SLOT) + 1) & 3, i, 1);                             \
      nxtB[i * 2 + 0] = LDB(((SLOT) + 1) & 3, i, 0);                             \
      nxtB[i * 2 + 1] = LDB(((SLOT) + 1) & 3, i, 1);                             \
    }                                                                            \
    __builtin_amdgcn_s_setprio(1);                                               \
    _Pragma("unroll")                                                            \
    for (int ks = 0; ks < 2; ks++)                                               \
      _Pragma("unroll")                                                          \
      for (int i = 0; i < 2; i++)                                                \
        _Pragma("unroll")                                                        \
        for (int j = 0; j < 2; j++)                                              \
          acc[2 + i][j] = __builtin_amdgcn_mfma_f32_32x32x16_bf16(               \
              af1_[i * 2 + ks], curB[j * 2 + ks], acc[2 + i][j], 0, 0, 0);       \
    __builtin_amdgcn_s_setprio(0);                                               \
    asm volatile("s_waitcnt vmcnt(4)" ::: "memory");                             \
    __builtin_amdgcn_s_barrier();                                                \
  } while (0)

  for (int t = 0; t < NT; t += 4) {
    BODY(t + 0, 0, afA, bfA, afB, bfB);
    BODY(t + 1, 1, afB, bfB, afA, bfA);
    BODY(t + 2, 2, afA, bfA, afB, bfB);
    BODY(t + 3, 3, afB, bfB, afA, bfA);
  }
#undef BODY
#undef LDA
#undef LDB

  // drain leftover clamped-tail stages before LDS goes away
  asm volatile("s_waitcnt vmcnt(0)" ::: "memory");

  // ---- epilogue: 32x32 C/D layout col=lane&31, row=(reg&3)+8*(reg>>2)+4*(lane>>5)
  const int c32 = lane & 31;
  const int rq4 = (lane >> 5) * 4;
#pragma unroll
  for (int j = 0; j < 2; j++) {
    const long n = bn + wn * 64 + j * 32 + c32;
    const float bv = bias[n];
#pragma unroll
    for (int i = 0; i < 4; i++) {
      const long m0 = bm + wm * 128 + i * 32 + rq4;
#pragma unroll
      for (int reg = 0; reg < 16; reg++) {
        const int row = (reg & 3) + 8 * (reg >> 2);
        C[(m0 + row) * (long)N + n] = acc[i][j][reg] + bv;
      }
    }
  }
}

// ---- fallback (only if d_ws is too small): exact fp32, slow but correct ----

__global__ void naive_kernel(const float* __restrict__ x, const float* __restrict__ w,
                             const float* __restrict__ bias, const float* __restrict__ m,
                             float* __restrict__ out) {
  size_t idx = (size_t)blockIdx.x * 256 + threadIdx.x;
  int o = (int)(idx % OUT_F);
  size_t b = idx / OUT_F;
  float s = bias[o];
  const float* xr = x + b * IN_F;
  const float* wr = w + (size_t)o * IN_F;
  const float* mr = m + (size_t)o * IN_F;
  for (int k = 0; k < IN_F; k++) s += xr[k] * wr[k] * mr[k];
  out[idx] = s;
}

extern "C" void kernel_launch(void* const* d_in, const int* in_sizes, int n_in,
                              void* d_out, int out_size, void* d_ws, size_t ws_size,
                              hipStream_t stream) {
  const float* x = (const float*)d_in[0];
  const float* w = (const float*)d_in[1];
  const float* bias = (const float*)d_in[2];
  const float* mask = (const float*)d_in[3];
  float* out = (float*)d_out;

  const size_t xb_elems = (size_t)BATCH * IN_F;       // 33.5M bf16 = 64 MB
  const size_t wm_elems = (size_t)OUT_F * IN_F;       // 4.2M bf16 = 8 MB
  const size_t need = (xb_elems + wm_elems) * sizeof(u16);

  if (ws_size >= need) {
    u16* xb = (u16*)d_ws;
    u16* wm = xb + xb_elems;
    const uint32_t nblk = (uint32_t)((xb_elems + wm_elems) / 4 / 256);
    cvt_fused<<<nblk, 256, 0, stream>>>((const float4*)x, (const float4*)w,
                                        (const float4*)mask, xb, wm);
    gemm_bf16<<<dim3(OUT_F / 256, BATCH / 256), 512, 0, stream>>>(xb, wm, bias, out);
  } else {
    naive_kernel<<<(uint32_t)(((size_t)BATCH * OUT_F) / 256), 256, 0, stream>>>(x, w, bias, mask, out);
  }
}